// Round 9
// baseline (376.533 us; speedup 1.0000x reference)
//
#include <hip/hip_runtime.h>

#define NNODES 50000
#define NEDGES 800000
#define NGRAPH 500
#define CH 100
#define CIN0 33
#define BN_EPS 1e-5f
#define NSHARD 8
#define SHSTRIDE 1024   // floats per shard: [4 layers][sum128|sq128]
#define NBUK 196        // = ceil(NNODES/256); bucket b covers dst nodes [b*256, b*256+256)
#define BEPW 2048       // edges per workgroup in k_bin

#define SCAN_TPB 256
#define SCAN_IPT 4
#define SCAN_TILE (SCAN_TPB * SCAN_IPT)
#define SCAN_BLOCKS ((NNODES + SCAN_TILE - 1) / SCAN_TILE)

typedef __attribute__((ext_vector_type(8))) short short8;
typedef __attribute__((ext_vector_type(4))) float f32x4;

// pack two fp32 into (bf16(x) | bf16(y)<<16), round-to-nearest-even
__device__ inline unsigned pack_bf16(float x, float y) {
    unsigned xb = __float_as_uint(x);
    unsigned yb = __float_as_uint(y);
    xb += 0x7FFF + ((xb >> 16) & 1);
    yb += 0x7FFF + ((yb >> 16) & 1);
    return (xb >> 16) | (yb & 0xFFFF0000u);
}
__device__ inline float unp_lo(unsigned v) { return __uint_as_float(v << 16); }
__device__ inline float unp_hi(unsigned v) { return __uint_as_float(v & 0xFFFF0000u); }

// ---------------- fused prep: zero counters/stats/pool, pack x (unscaled bf16),
// pack W hi/lo, pack W0 hi/lo, zero Z sentinels ----------------
__global__ void k_prep(const float* __restrict__ x, unsigned* __restrict__ xb,
                       int* __restrict__ cnt, float* __restrict__ stats,
                       float* __restrict__ gbuf,
                       const float* __restrict__ Wrest, unsigned* __restrict__ whi,
                       unsigned* __restrict__ wlo,
                       const float* __restrict__ W0, unsigned* __restrict__ w0hi,
                       unsigned* __restrict__ w0lo,
                       unsigned* __restrict__ Z0, unsigned* __restrict__ Z1) {
    int i = blockIdx.x * blockDim.x + threadIdx.x;
    if (i < (NNODES + 1) * 17) {           // pack x -> bf16 (UNSCALED; dinv rides on edges)
        int r = i / 17, s = i - r * 17;
        if (r >= NNODES) xb[i] = 0u;       // zero sentinel row
        else {
            float a = x[r * CIN0 + 2 * s];
            float b = (2 * s + 1 < CIN0) ? x[r * CIN0 + 2 * s + 1] : 0.f;
            xb[i] = pack_bf16(a, b);
        }
    }
    if (i < NNODES) { cnt[i] = 0; gbuf[i] = 0.f; }   // NGRAPH*CH == NNODES
    if (i < NSHARD * SHSTRIDE) stats[i] = 0.f;
    if (i < 3 * 112 * 64) {                // Wrest^T hi/lo, K padded to 128
        int l = i / 7168, rem = i % 7168;
        int c = rem >> 6, ku = rem & 63;
        int k0 = 2 * ku;
        float w0 = 0.f, w1 = 0.f;
        if (c < CH && k0 < CH) {
            w0 = Wrest[l * 10000 + k0 * CH + c];
            if (k0 + 1 < CH) w1 = Wrest[l * 10000 + (k0 + 1) * CH + c];
        }
        unsigned hh = pack_bf16(w0, w1);
        whi[i] = hh;
        wlo[i] = pack_bf16(w0 - unp_lo(hh), w1 - unp_hi(hh));
    }
    if (i < 112 * 32) {                    // W0^T hi/lo, K padded to 64
        int c = i >> 5, ku = i & 31;
        int k0 = 2 * ku;
        float w0 = 0.f, w1 = 0.f;
        if (c < CH && k0 < CIN0) {
            w0 = W0[k0 * CH + c];
            if (k0 + 1 < CIN0) w1 = W0[(k0 + 1) * CH + c];
        }
        unsigned hh = pack_bf16(w0, w1);
        w0hi[i] = hh;
        w0lo[i] = pack_bf16(w0 - unp_lo(hh), w1 - unp_hi(hh));
    }
    if (i < 50) {                          // zero Z sentinel rows (read via pad edges)
        Z0[(size_t)NNODES * 50 + i] = 0u;
        Z1[(size_t)NNODES * 50 + i] = 0u;
    }
}

// ---------------- in-degree histogram over dst ----------------
__global__ void k_hist(const int* __restrict__ dst, int* __restrict__ cnt) {
    int e = blockIdx.x * blockDim.x + threadIdx.x;
    if (e < NEDGES) atomicAdd(&cnt[dst[e]], 1);
}

// ---------------- exclusive scan of padded counts -> rowptr; dinv; per-bucket edge counts ----------------
__global__ void k_scan1(const int* __restrict__ cnt, int* __restrict__ rowptr,
                        int* __restrict__ blkSums, float* __restrict__ dinv,
                        int* __restrict__ bcnt) {
    __shared__ int ts[SCAN_TPB];
    __shared__ int bsum[4];
    int tid = threadIdx.x;
    if (tid < 4) bsum[tid] = 0;
    int base = blockIdx.x * SCAN_TILE + tid * SCAN_IPT;
    int v[SCAN_IPT];
    int s = 0, cact = 0;
    #pragma unroll
    for (int j = 0; j < SCAN_IPT; ++j) {
        int i = base + j;
        int c = (i < NNODES) ? cnt[i] : 0;
        if (i < NNODES) dinv[i] = rsqrtf((float)(c + 1));
        v[j] = (c + 7) & ~7;   // pad each row to multiple of 8 edges
        s += v[j];
        cact += c;
    }
    ts[tid] = s;
    __syncthreads();
    atomicAdd(&bsum[(tid * SCAN_IPT) >> 8], cact);
    for (int off = 1; off < SCAN_TPB; off <<= 1) {
        int add = (tid >= off) ? ts[tid - off] : 0;
        __syncthreads();
        ts[tid] += add;
        __syncthreads();
    }
    int run = ts[tid] - s;
    #pragma unroll
    for (int j = 0; j < SCAN_IPT; ++j) {
        int i = base + j;
        if (i < NNODES) rowptr[i] = run;
        run += v[j];
    }
    if (tid == SCAN_TPB - 1) blkSums[blockIdx.x] = ts[tid];
    if (tid < 4) {
        int b = blockIdx.x * 4 + tid;
        if (b < NBUK) bcnt[b] = bsum[tid];
    }
}

// ---------------- scan2 (block offsets, serial) + bucket scan, one 256-thr block ----------------
__global__ void k_scan2b(const int* __restrict__ blkSums, int* __restrict__ blkOff,
                         int* __restrict__ rp2, const int* __restrict__ bcnt,
                         int* __restrict__ bbase, int* __restrict__ gbkcur) {
    __shared__ int ts[256];
    int t = threadIdx.x;
    if (t == 0) {
        int run = 0;
        for (int i = 0; i < SCAN_BLOCKS; ++i) { blkOff[i] = run; run += blkSums[i]; }
        rp2[NNODES] = run;   // total padded edges (finalized rowptr end)
    }
    int v = (t < NBUK) ? bcnt[t] : 0;
    ts[t] = v;
    __syncthreads();
    for (int off = 1; off < 256; off <<= 1) {
        int a = (t >= off) ? ts[t - off] : 0;
        __syncthreads();
        ts[t] += a;
        __syncthreads();
    }
    int excl = ts[t] - v;
    if (t < NBUK) { bbase[t] = excl; gbkcur[t] = excl; }
    if (t == NBUK - 1) bbase[NBUK] = ts[t];
}

// ---------------- phase A: bin edges by dst-bucket; pack (src | bf16(dinv[src])<<16) ----------------
__global__ __launch_bounds__(256) void k_bin(const int* __restrict__ src,
                                             const int* __restrict__ dst,
                                             const float* __restrict__ dinv,
                                             int* __restrict__ gbkcur,
                                             uint2* __restrict__ ebuf) {
    __shared__ int hist[256], ofs[256], lcnt[256], bbaseL[256];
    __shared__ int totS;
    __shared__ uint2 stage[BEPW];   // 16 KB
    int tid = threadIdx.x;
    hist[tid] = 0; lcnt[tid] = 0;
    __syncthreads();
    int e0 = blockIdx.x * BEPW;
    unsigned sv[8]; int dv[8]; bool ok[8];
    #pragma unroll
    for (int j = 0; j < 8; ++j) {
        int e = e0 + j * 256 + tid;
        ok[j] = e < NEDGES;
        int s = ok[j] ? src[e] : 0;
        dv[j] = ok[j] ? dst[e] : 0;
        if (ok[j]) {
            unsigned db = __float_as_uint(dinv[s]);
            db += 0x7FFF + ((db >> 16) & 1);            // rne bf16
            sv[j] = (unsigned)s | (db & 0xFFFF0000u);   // src in low16, dinv_src bf16 in high16
            atomicAdd(&hist[dv[j] >> 8], 1);
        }
    }
    __syncthreads();
    int v = hist[tid];
    ofs[tid] = v;
    __syncthreads();
    for (int off = 1; off < 256; off <<= 1) {
        int a = (tid >= off) ? ofs[tid - off] : 0;
        __syncthreads();
        ofs[tid] += a;
        __syncthreads();
    }
    if (tid == 255) totS = ofs[255];
    int excl = ofs[tid] - v;
    __syncthreads();
    ofs[tid] = excl;
    if (tid < NBUK && v > 0) bbaseL[tid] = atomicAdd(&gbkcur[tid], v);
    __syncthreads();
    #pragma unroll
    for (int j = 0; j < 8; ++j) {
        if (ok[j]) {
            int b = dv[j] >> 8;
            int idx = atomicAdd(&lcnt[b], 1);
            stage[ofs[b] + idx] = make_uint2(sv[j], (unsigned)dv[j]);
        }
    }
    __syncthreads();
    int tot = totS;
    #pragma unroll
    for (int j = 0; j < 8; ++j) {
        int slot = j * 256 + tid;
        if (slot < tot) {
            uint2 p = stage[slot];
            int b = (int)(p.y >> 8);
            ebuf[bbaseL[b] + (slot - ofs[b])] = p;
        }
    }
}

// ---------------- phase B: place edges into padded CSR; LDS cursors; pad fill;
// also finalizes rowptr (+ scan-block offset) into rp2 ----------------
__global__ __launch_bounds__(256) void k_place(const uint2* __restrict__ ebuf,
                                               const int* __restrict__ bbase,
                                               const int* __restrict__ rowptr,
                                               const int* __restrict__ blkOff,
                                               int* __restrict__ rp2,
                                               unsigned* __restrict__ ew) {
    __shared__ int lcur[256];
    int b = blockIdx.x, t = threadIdx.x;
    int lo = b * 256;
    int n = NNODES - lo; if (n > 256) n = 256;
    if (t < n) {
        int node = lo + t;
        int base = rowptr[node] + blkOff[node >> 10];
        lcur[t] = base;
        rp2[node] = base;
    }
    __syncthreads();
    int e0 = bbase[b], e1 = bbase[b + 1];
    for (int e = e0 + t; e < e1; e += 256) {
        uint2 p = ebuf[e];
        int pos = atomicAdd(&lcur[p.y & 255], 1);
        ew[pos] = p.x;
    }
    __syncthreads();
    if (t < n) {
        int idx = lo + t + 1;
        int end = (idx < NNODES) ? (rowptr[idx] + blkOff[idx >> 1024 == 0 ? (idx >> 10) : (idx >> 10)]) : rp2[NNODES];
        end = (idx < NNODES) ? (rowptr[idx] + blkOff[idx >> 10]) : rp2[NNODES];
        for (int q = lcur[t]; q < end; ++q) ew[q] = NNODES;   // sentinel: weight bits = 0
    }
}

// ---------------- FUSED [BN+ReLU] + gather + MFMA GEMM ----------------
// a_i = dinv_i*( sum_e w_e*f(row_src) + dinv_i*f(row_i) ), w_e = bf16(dinv_src) from ew.
// f = relu(BN(.)) for CH layers (per-lane channel constants, computed once/wave) or
// identity for layer 0. Gather writes the swizzled LDS A-tile; MFMA consumes W in
// KS 14 KB hi/lo chunks through one staging buffer (~31.5 KB LDS, 4 blocks/CU).
// Next W chunk is register-prefetched during MFMAs so only ds_write sits between barriers.
// POOL: instead of storing Z, atomically accumulate raw per-graph channel sums
// (BN-affine applied later in k_out via linearity) — kills the k_pool pass.
template<int CPACK, int RB, int KS, bool BN, bool POOL>
__global__ __launch_bounds__(512, 8) void k_fused(
    const unsigned* __restrict__ h, const unsigned* __restrict__ Whi,
    const unsigned* __restrict__ Wlo, const float* __restrict__ bias,
    const int* __restrict__ rowptr, const unsigned* __restrict__ ew,
    const float* __restrict__ dinv,
    const float* __restrict__ pgsum, const float* __restrict__ pgsq,
    const float* __restrict__ gamma, const float* __restrict__ beta,
    const int* __restrict__ batch, float* __restrict__ gpool,
    unsigned* __restrict__ Zout, float* __restrict__ gsum, float* __restrict__ gsq) {
    constexpr int RBY = KS * 64;                  // A-tile row bytes
    __shared__ __align__(16) unsigned char aS[64 * RBY];
    __shared__ __align__(16) unsigned char wB[112 * 128];   // 14 KB W chunk
    __shared__ float sSum[CH], sSq[CH];
    int tid = threadIdx.x;
    for (int i = tid; i < CH; i += 512) { sSum[i] = 0.f; sSq[i] = 0.f; }
    // stage W chunk 0 (hi, k-pair 0)
    for (int idx = tid; idx < 112 * 8; idx += 512) {
        int c = idx >> 3, j = idx & 7;
        uint4 v = *(const uint4*)(Whi + c * (KS * 16) + j * 4);
        *(uint4*)(wB + ((unsigned)(c * 128 + j * 16) ^ ((c & 7) << 4))) = v;
    }
    int w = tid >> 6, lane = tid & 63;
    int row0 = blockIdx.x * 64;
    const char* __restrict__ hb = (const char*)h;
    bool act = lane < CPACK;
    unsigned l4 = (unsigned)(lane << 2);
    // per-lane (= per channel-pair) BN constants, once per wave
    float scx = 0.f, shx = 0.f, scy = 0.f, shy = 0.f;
    if (BN && act) {
        float sx = 0.f, sy = 0.f, qx = 0.f, qy = 0.f;
        #pragma unroll
        for (int sh = 0; sh < NSHARD; ++sh) {
            float2 s2 = ((const float2*)(pgsum + sh * SHSTRIDE))[lane];
            float2 q2 = ((const float2*)(pgsq + sh * SHSTRIDE))[lane];
            sx += s2.x; sy += s2.y; qx += q2.x; qy += q2.y;
        }
        constexpr float invN = 1.f / NNODES;
        float2 g2 = ((const float2*)gamma)[lane];
        float2 b2 = ((const float2*)beta)[lane];
        float mx = sx * invN, my = sy * invN;
        float vx = qx * invN - mx * mx, vy = qy * invN - my * my;
        scx = g2.x * rsqrtf(vx + BN_EPS); shx = b2.x - mx * scx;
        scy = g2.y * rsqrtf(vy + BN_EPS); shy = b2.y - my * scy;
    }
    // ---- gather phase: wave w builds rows w*8 .. w*8+7 (R6-proven single-row loop) ----
    for (int ni = 0; ni < 8; ++ni) {
        int r = w * 8 + ni;
        int node = row0 + r;
        float ax = 0.f, ay = 0.f, di = 0.f;
        if (node < NNODES) {
            int p0 = __builtin_amdgcn_readfirstlane(rowptr[node]);
            int p1 = __builtin_amdgcn_readfirstlane(rowptr[node + 1]);
            di = dinv[node];
            if (act) {
                unsigned hv = h[(size_t)node * CPACK + lane];   // self term
                float fx = unp_lo(hv), fy = unp_hi(hv);
                if (BN) {
                    fx = fmaxf(fmaf(fx, scx, shx), 0.f);
                    fy = fmaxf(fmaf(fy, scy, shy), 0.f);
                }
                ax = di * fx; ay = di * fy;
            }
            const uint4* __restrict__ E4 = (const uint4*)(ew + p0);
            int n8 = (p1 - p0) >> 3;
            for (int q = 0; q < n8; ++q) {
                uint4 ea = E4[2 * q];
                uint4 eb = E4[2 * q + 1];
                unsigned ee[8] = {ea.x, ea.y, ea.z, ea.w, eb.x, eb.y, eb.z, eb.w};
                if (act) {
                    unsigned v[8];
                    #pragma unroll
                    for (int t = 0; t < 8; ++t)
                        v[t] = *(const unsigned*)(hb + (ee[t] & 0xFFFFu) * (unsigned)RB + l4);
                    #pragma unroll
                    for (int t = 0; t < 8; ++t) {
                        float vx = unp_lo(v[t]), vy = unp_hi(v[t]);
                        if (BN) {
                            vx = fmaxf(fmaf(vx, scx, shx), 0.f);
                            vy = fmaxf(fmaf(vy, scy, shy), 0.f);
                        }
                        float wgt = unp_hi(ee[t]);   // bf16(dinv_src); 0 on pad sentinels
                        ax = fmaf(wgt, vx, ax); ay = fmaf(wgt, vy, ay);
                    }
                }
            }
        }
        unsigned val = act ? pack_bf16(di * ax, di * ay) : 0u;
        if (lane < RBY / 4)
            *(unsigned*)(aS + ((unsigned)(r * RBY + lane * 4) ^ ((r & 7) << 4))) = val;
    }
    __syncthreads();
    // ---- MFMA phase: KS chunks; next chunk register-prefetched during MFMAs ----
    int wm = w & 3, wh = w >> 2;          // m-tile, n-half (wh=0: nt 0..3, wh=1: nt 4..6)
    int lr = lane & 15, lg = lane >> 4;
    f32x4 acc[4];
    #pragma unroll
    for (int nt = 0; nt < 4; ++nt) acc[nt] = (f32x4){0.f, 0.f, 0.f, 0.f};
    int ar = wm * 16 + lr;
    unsigned aswz = (unsigned)((ar & 7) << 4);
    uint4 pv0, pv1;
    #pragma unroll
    for (int ch = 0; ch < KS; ++ch) {
        if (ch + 1 < KS) {   // prefetch next chunk into registers (overlaps MFMAs)
            const unsigned* Wp = (ch + 1 >= KS / 2) ? Wlo : Whi;
            int pn = (KS > 2) ? ((ch + 1) & 1) : 0;
            {
                int c = tid >> 3, j = tid & 7;
                pv0 = *(const uint4*)(Wp + c * (KS * 16) + pn * 32 + j * 4);
            }
            if (tid < 384) {
                int idx = tid + 512;
                int c = idx >> 3, j = idx & 7;
                pv1 = *(const uint4*)(Wp + c * (KS * 16) + pn * 32 + j * 4);
            }
        }
        int p = (KS > 2) ? (ch & 1) : 0;
        #pragma unroll
        for (int ksl = 0; ksl < 2; ++ksl) {
            int ks = p * 2 + ksl;
            short8 af = *(const short8*)(aS + ((unsigned)(ar * RBY + ks * 64 + lg * 16) ^ aswz));
            #pragma unroll
            for (int nt = 0; nt < 4; ++nt) {
                if (wh && nt == 3) continue;   // only 7 n-tiles total
                int c = (wh * 4 + nt) * 16 + lr;
                short8 bb = *(const short8*)(wB + ((unsigned)(c * 128 + ksl * 64 + lg * 16) ^ ((c & 7) << 4)));
                acc[nt] = __builtin_amdgcn_mfma_f32_16x16x32_bf16(af, bb, acc[nt], 0, 0, 0);
            }
        }
        if (ch + 1 < KS) {
            __syncthreads();   // all reads of current chunk done
            {
                int c = tid >> 3, j = tid & 7;
                *(uint4*)(wB + ((unsigned)(c * 128 + j * 16) ^ ((c & 7) << 4))) = pv0;
            }
            if (tid < 384) {
                int idx = tid + 512;
                int c = idx >> 3, j = idx & 7;
                *(uint4*)(wB + ((unsigned)(c * 128 + j * 16) ^ ((c & 7) << 4))) = pv1;
            }
            __syncthreads();
        }
    }
    // epilogue: bias; then either packed bf16 store (layers 0-2) or per-graph
    // raw-sum atomic pooling (layer 3); BN stats always.
    int g4[4];
    if (POOL) {
        #pragma unroll
        for (int r = 0; r < 4; ++r) {
            int row = row0 + wm * 16 + lg * 4 + r;
            g4[r] = (row < NNODES) ? batch[row] : 0;
        }
    }
    #pragma unroll
    for (int nt = 0; nt < 4; ++nt) {
        if (wh && nt == 3) continue;
        int c = (wh * 4 + nt) * 16 + lr;
        bool cok = c < CH;
        float bcol = cok ? bias[c] : 0.f;
        float s = 0.f, q = 0.f;
        #pragma unroll
        for (int r = 0; r < 4; ++r) {
            int row = row0 + wm * 16 + lg * 4 + r;
            float z = acc[nt][r] + bcol;
            float zo = __shfl_xor(z, 1);
            if (cok && row < NNODES) {
                if (POOL) {
                    atomicAdd(&gpool[g4[r] * CH + c], z);
                } else {
                    if ((lane & 1) == 0)
                        Zout[(size_t)row * 50 + (c >> 1)] = pack_bf16(z, zo);
                }
                s += z; q += z * z;
            }
        }
        s += __shfl_xor(s, 16); s += __shfl_xor(s, 32);
        q += __shfl_xor(q, 16); q += __shfl_xor(q, 32);
        if (lane < 16 && cok) { atomicAdd(&sSum[c], s); atomicAdd(&sSq[c], q); }
    }
    __syncthreads();
    int sh = (blockIdx.x & (NSHARD - 1)) * SHSTRIDE;
    if (tid < CH) { atomicAdd(&gsum[sh + tid], sSum[tid]); atomicAdd(&gsq[sh + tid], sSq[tid]); }
}

// ---------------- out = leakyrelu( (BN-affine of raw pooled sums) @ Wout + bout, 0.1 ) ----------------
// gS[c] = scx_c * S[gid][c] + n_gid * shx_c  (linearity of BN over the pooled sum)
__global__ __launch_bounds__(256) void k_out(const float* __restrict__ g,
                                             const int* __restrict__ batch,
                                             const float* __restrict__ gsum,
                                             const float* __restrict__ gsq,
                                             const float* __restrict__ gamma,
                                             const float* __restrict__ beta,
                                             const float* __restrict__ Wout,
                                             const float* __restrict__ bout,
                                             float* __restrict__ out) {
    __shared__ float gS[CH];
    __shared__ int se[2];
    int gid = blockIdx.x, tid = threadIdx.x;
    if (tid == 0) {
        int lo = 0, hi = NNODES;
        while (lo < hi) { int m = (lo + hi) >> 1; if (batch[m] < gid) lo = m + 1; else hi = m; }
        se[0] = lo;
        hi = NNODES;
        while (lo < hi) { int m = (lo + hi) >> 1; if (batch[m] < gid + 1) lo = m + 1; else hi = m; }
        se[1] = lo;
    }
    __syncthreads();
    float n = (float)(se[1] - se[0]);
    if (tid < 50) {
        float su = 0.f, sv = 0.f, qu = 0.f, qv = 0.f;
        #pragma unroll
        for (int sh = 0; sh < NSHARD; ++sh) {
            float2 s2 = ((const float2*)(gsum + sh * SHSTRIDE))[tid];
            float2 q2 = ((const float2*)(gsq + sh * SHSTRIDE))[tid];
            su += s2.x; sv += s2.y; qu += q2.x; qv += q2.y;
        }
        constexpr float invN = 1.f / NNODES;
        float2 g2 = ((const float2*)gamma)[tid];
        float2 b2 = ((const float2*)beta)[tid];
        float mx = su * invN, my = sv * invN;
        float vx = qu * invN - mx * mx, vy = qv * invN - my * my;
        float scx = g2.x * rsqrtf(vx + BN_EPS), shx = b2.x - mx * scx;
        float scy = g2.y * rsqrtf(vy + BN_EPS), shy = b2.y - my * scy;
        float2 S = ((const float2*)(g + gid * CH))[tid];
        gS[2 * tid] = S.x * scx + n * shx;
        gS[2 * tid + 1] = S.y * scy + n * shy;
    }
    __syncthreads();
    if (tid >= 200) return;
    float acc = bout[tid];
    for (int k = 0; k < CH; ++k) acc += gS[k] * Wout[k * 200 + tid];
    out[gid * 200 + tid] = acc > 0.f ? acc : 0.1f * acc;
}

extern "C" void kernel_launch(void* const* d_in, const int* in_sizes, int n_in,
                              void* d_out, int out_size, void* d_ws, size_t ws_size,
                              hipStream_t stream) {
    const float* x = (const float*)d_in[0];
    const int* ei = (const int*)d_in[1];
    const int* batch = (const int*)d_in[2];
    const float* W0 = (const float*)d_in[3];
    const float* Wrest = (const float*)d_in[4];
    const float* b = (const float*)d_in[5];
    const float* gamma = (const float*)d_in[6];
    const float* beta = (const float*)d_in[7];
    const float* Wout = (const float*)d_in[8];
    const float* bout = (const float*)d_in[9];
    float* out = (float*)d_out;
    const int* srcA = ei;
    const int* dstA = ei + NEDGES;

    char* wsb = (char*)d_ws;
    size_t off = 0;
    auto alloc = [&](size_t elems) -> void* {
        void* p = (void*)(wsb + off);
        off += ((elems + 7) & ~(size_t)7) * 4;
        return p;
    };
    int* cnt = (int*)alloc(NNODES);
    int* rowptr = (int*)alloc(NNODES + 1);   // pre-offset (per-scan-block local)
    int* rp2 = (int*)alloc(NNODES + 1);      // finalized rowptr
    float* dinv = (float*)alloc(NNODES);
    int* scanBlk = (int*)alloc(64);
    int* scanOff = (int*)alloc(64);
    int* bcnt = (int*)alloc(256);
    int* bbase = (int*)alloc(256);
    int* gbkcur = (int*)alloc(256);
    float* stats = (float*)alloc(NSHARD * SHSTRIDE);
    unsigned* ew = (unsigned*)alloc((size_t)NEDGES + 8 * NNODES);  // padded CSR (src|dinv_bf16)
    uint2* ebuf = (uint2*)alloc(2 * (size_t)NEDGES);               // bucket-major staging
    unsigned* xb = (unsigned*)alloc((size_t)(NNODES + 1) * 17);
    unsigned* wthi = (unsigned*)alloc(3 * 112 * 64);
    unsigned* wtlo = (unsigned*)alloc(3 * 112 * 64);
    unsigned* w0hi = (unsigned*)alloc(112 * 32);
    unsigned* w0lo = (unsigned*)alloc(112 * 32);
    unsigned* Z0 = (unsigned*)alloc((size_t)(NNODES + 1) * 50);    // ping-pong activations
    unsigned* Z1 = (unsigned*)alloc((size_t)(NNODES + 1) * 50);
    float* gbuf = (float*)alloc((size_t)NGRAPH * CH);              // raw per-graph channel sums
    (void)ws_size; (void)n_in; (void)in_sizes; (void)out_size;

    hipLaunchKernelGGL(k_prep, dim3(((NNODES + 1) * 17 + 255) / 256), dim3(256), 0, stream,
                       x, xb, cnt, stats, gbuf, Wrest, wthi, wtlo, W0, w0hi, w0lo, Z0, Z1);
    hipLaunchKernelGGL(k_hist, dim3((NEDGES + 255) / 256), dim3(256), 0, stream, dstA, cnt);
    hipLaunchKernelGGL(k_scan1, dim3(SCAN_BLOCKS), dim3(SCAN_TPB), 0, stream,
                       cnt, rowptr, scanBlk, dinv, bcnt);
    hipLaunchKernelGGL(k_scan2b, dim3(1), dim3(256), 0, stream,
                       scanBlk, scanOff, rp2, bcnt, bbase, gbkcur);
    hipLaunchKernelGGL(k_bin, dim3((NEDGES + BEPW - 1) / BEPW), dim3(256), 0, stream,
                       srcA, dstA, dinv, gbkcur, ebuf);
    hipLaunchKernelGGL(k_place, dim3(NBUK), dim3(256), 0, stream,
                       ebuf, bbase, rowptr, scanOff, rp2, ew);

    const int NTILE = (NNODES + 63) / 64;
    // ---- layer 0: fused gather(xb, identity) + MFMA (K=64) -> Z0 ----
    hipLaunchKernelGGL((k_fused<17, 68, 2, false, false>), dim3(NTILE), dim3(512), 0, stream,
                       xb, w0hi, w0lo, b, rp2, ew, dinv,
                       (const float*)nullptr, (const float*)nullptr,
                       (const float*)nullptr, (const float*)nullptr,
                       (const int*)nullptr, (float*)nullptr,
                       Z0, stats + 0 * 128, stats + 512 + 0 * 128);
    // ---- layers 1..2: fused BN+relu+gather(Zprev) + MFMA (K=128), ping-pong ----
    unsigned* Zp[3] = {Z0, Z1, Z0};
    for (int l = 1; l < 3; ++l) {
        hipLaunchKernelGGL((k_fused<50, 200, 4, true, false>), dim3(NTILE), dim3(512), 0, stream,
                           Zp[l - 1], wthi + (l - 1) * 7168, wtlo + (l - 1) * 7168, b + l * CH,
                           rp2, ew, dinv,
                           stats + (l - 1) * 128, stats + 512 + (l - 1) * 128,
                           gamma + (l - 1) * CH, beta + (l - 1) * CH,
                           (const int*)nullptr, (float*)nullptr,
                           Zp[l], stats + l * 128, stats + 512 + l * 128);
    }
    // ---- layer 3: fused BN+relu+gather + MFMA + in-epilogue raw pooling (no Z store) ----
    hipLaunchKernelGGL((k_fused<50, 200, 4, true, true>), dim3(NTILE), dim3(512), 0, stream,
                       Zp[2], wthi + 2 * 7168, wtlo + 2 * 7168, b + 3 * CH,
                       rp2, ew, dinv,
                       stats + 2 * 128, stats + 512 + 2 * 128,
                       gamma + 2 * CH, beta + 2 * CH,
                       batch, gbuf,
                       (unsigned*)nullptr, stats + 3 * 128, stats + 512 + 3 * 128);
    hipLaunchKernelGGL(k_out, dim3(NGRAPH), dim3(256), 0, stream,
                       gbuf, batch, stats + 3 * 128, stats + 512 + 3 * 128,
                       gamma + 3 * CH, beta + 3 * CH, Wout, bout, out);
}

// Round 10
// 341.482 us; speedup vs baseline: 1.1026x; 1.1026x over previous
//
#include <hip/hip_runtime.h>

#define NNODES 50000
#define NEDGES 800000
#define NGRAPH 500
#define CH 100
#define CIN0 33
#define BN_EPS 1e-5f
#define NSHARD 8
#define SHSTRIDE 1024   // floats per shard: [4 layers][sum128|sq128]
#define NBUK 196        // = ceil(NNODES/256); bucket b covers dst nodes [b*256, b*256+256)
#define BEPW 2048       // edges per workgroup in k_bin
#define GSPAN 8         // max graphs spanned by a 64-row tile (LDS pool buckets)

#define SCAN_TPB 256
#define SCAN_IPT 4
#define SCAN_TILE (SCAN_TPB * SCAN_IPT)
#define SCAN_BLOCKS ((NNODES + SCAN_TILE - 1) / SCAN_TILE)

typedef __attribute__((ext_vector_type(8))) short short8;
typedef __attribute__((ext_vector_type(4))) float f32x4;

// pack two fp32 into (bf16(x) | bf16(y)<<16), round-to-nearest-even
__device__ inline unsigned pack_bf16(float x, float y) {
    unsigned xb = __float_as_uint(x);
    unsigned yb = __float_as_uint(y);
    xb += 0x7FFF + ((xb >> 16) & 1);
    yb += 0x7FFF + ((yb >> 16) & 1);
    return (xb >> 16) | (yb & 0xFFFF0000u);
}
__device__ inline float unp_lo(unsigned v) { return __uint_as_float(v << 16); }
__device__ inline float unp_hi(unsigned v) { return __uint_as_float(v & 0xFFFF0000u); }

// ---------------- fused prep: zero counters/stats/pool, pack x (unscaled bf16),
// pack W hi/lo, pack W0 hi/lo, zero Z sentinels ----------------
__global__ void k_prep(const float* __restrict__ x, unsigned* __restrict__ xb,
                       int* __restrict__ cnt, float* __restrict__ stats,
                       float* __restrict__ gbuf,
                       const float* __restrict__ Wrest, unsigned* __restrict__ whi,
                       unsigned* __restrict__ wlo,
                       const float* __restrict__ W0, unsigned* __restrict__ w0hi,
                       unsigned* __restrict__ w0lo,
                       unsigned* __restrict__ Z0, unsigned* __restrict__ Z1) {
    int i = blockIdx.x * blockDim.x + threadIdx.x;
    if (i < (NNODES + 1) * 17) {           // pack x -> bf16 (UNSCALED; dinv rides on edges)
        int r = i / 17, s = i - r * 17;
        if (r >= NNODES) xb[i] = 0u;       // zero sentinel row
        else {
            float a = x[r * CIN0 + 2 * s];
            float b = (2 * s + 1 < CIN0) ? x[r * CIN0 + 2 * s + 1] : 0.f;
            xb[i] = pack_bf16(a, b);
        }
    }
    if (i < NNODES) { cnt[i] = 0; gbuf[i] = 0.f; }   // NGRAPH*CH == NNODES
    if (i < NSHARD * SHSTRIDE) stats[i] = 0.f;
    if (i < 3 * 112 * 64) {                // Wrest^T hi/lo, K padded to 128
        int l = i / 7168, rem = i % 7168;
        int c = rem >> 6, ku = rem & 63;
        int k0 = 2 * ku;
        float w0 = 0.f, w1 = 0.f;
        if (c < CH && k0 < CH) {
            w0 = Wrest[l * 10000 + k0 * CH + c];
            if (k0 + 1 < CH) w1 = Wrest[l * 10000 + (k0 + 1) * CH + c];
        }
        unsigned hh = pack_bf16(w0, w1);
        whi[i] = hh;
        wlo[i] = pack_bf16(w0 - unp_lo(hh), w1 - unp_hi(hh));
    }
    if (i < 112 * 32) {                    // W0^T hi/lo, K padded to 64
        int c = i >> 5, ku = i & 31;
        int k0 = 2 * ku;
        float w0 = 0.f, w1 = 0.f;
        if (c < CH && k0 < CIN0) {
            w0 = W0[k0 * CH + c];
            if (k0 + 1 < CIN0) w1 = W0[(k0 + 1) * CH + c];
        }
        unsigned hh = pack_bf16(w0, w1);
        w0hi[i] = hh;
        w0lo[i] = pack_bf16(w0 - unp_lo(hh), w1 - unp_hi(hh));
    }
    if (i < 50) {                          // zero Z sentinel rows (read via pad edges)
        Z0[(size_t)NNODES * 50 + i] = 0u;
        Z1[(size_t)NNODES * 50 + i] = 0u;
    }
}

// ---------------- in-degree histogram over dst ----------------
__global__ void k_hist(const int* __restrict__ dst, int* __restrict__ cnt) {
    int e = blockIdx.x * blockDim.x + threadIdx.x;
    if (e < NEDGES) atomicAdd(&cnt[dst[e]], 1);
}

// ---------------- exclusive scan of padded counts -> rowptr; dinv; per-bucket edge counts ----------------
__global__ void k_scan1(const int* __restrict__ cnt, int* __restrict__ rowptr,
                        int* __restrict__ blkSums, float* __restrict__ dinv,
                        int* __restrict__ bcnt) {
    __shared__ int ts[SCAN_TPB];
    __shared__ int bsum[4];
    int tid = threadIdx.x;
    if (tid < 4) bsum[tid] = 0;
    int base = blockIdx.x * SCAN_TILE + tid * SCAN_IPT;
    int v[SCAN_IPT];
    int s = 0, cact = 0;
    #pragma unroll
    for (int j = 0; j < SCAN_IPT; ++j) {
        int i = base + j;
        int c = (i < NNODES) ? cnt[i] : 0;
        if (i < NNODES) dinv[i] = rsqrtf((float)(c + 1));
        v[j] = (c + 7) & ~7;   // pad each row to multiple of 8 edges
        s += v[j];
        cact += c;
    }
    ts[tid] = s;
    __syncthreads();
    atomicAdd(&bsum[(tid * SCAN_IPT) >> 8], cact);
    for (int off = 1; off < SCAN_TPB; off <<= 1) {
        int add = (tid >= off) ? ts[tid - off] : 0;
        __syncthreads();
        ts[tid] += add;
        __syncthreads();
    }
    int run = ts[tid] - s;
    #pragma unroll
    for (int j = 0; j < SCAN_IPT; ++j) {
        int i = base + j;
        if (i < NNODES) rowptr[i] = run;
        run += v[j];
    }
    if (tid == SCAN_TPB - 1) blkSums[blockIdx.x] = ts[tid];
    if (tid < 4) {
        int b = blockIdx.x * 4 + tid;
        if (b < NBUK) bcnt[b] = bsum[tid];
    }
}

// ---------------- scan2 (block offsets, serial) + bucket scan, one 256-thr block ----------------
__global__ void k_scan2b(const int* __restrict__ blkSums, int* __restrict__ blkOff,
                         int* __restrict__ rp2, const int* __restrict__ bcnt,
                         int* __restrict__ bbase, int* __restrict__ gbkcur) {
    __shared__ int ts[256];
    int t = threadIdx.x;
    if (t == 0) {
        int run = 0;
        for (int i = 0; i < SCAN_BLOCKS; ++i) { blkOff[i] = run; run += blkSums[i]; }
        rp2[NNODES] = run;   // total padded edges (finalized rowptr end)
    }
    int v = (t < NBUK) ? bcnt[t] : 0;
    ts[t] = v;
    __syncthreads();
    for (int off = 1; off < 256; off <<= 1) {
        int a = (t >= off) ? ts[t - off] : 0;
        __syncthreads();
        ts[t] += a;
        __syncthreads();
    }
    int excl = ts[t] - v;
    if (t < NBUK) { bbase[t] = excl; gbkcur[t] = excl; }
    if (t == NBUK - 1) bbase[NBUK] = ts[t];
}

// ---------------- phase A: bin edges by dst-bucket; pack (src | bf16(dinv[src])<<16) ----------------
__global__ __launch_bounds__(256) void k_bin(const int* __restrict__ src,
                                             const int* __restrict__ dst,
                                             const float* __restrict__ dinv,
                                             int* __restrict__ gbkcur,
                                             uint2* __restrict__ ebuf) {
    __shared__ int hist[256], ofs[256], lcnt[256], bbaseL[256];
    __shared__ int totS;
    __shared__ uint2 stage[BEPW];   // 16 KB
    int tid = threadIdx.x;
    hist[tid] = 0; lcnt[tid] = 0;
    __syncthreads();
    int e0 = blockIdx.x * BEPW;
    unsigned sv[8]; int dv[8]; bool ok[8];
    #pragma unroll
    for (int j = 0; j < 8; ++j) {
        int e = e0 + j * 256 + tid;
        ok[j] = e < NEDGES;
        int s = ok[j] ? src[e] : 0;
        dv[j] = ok[j] ? dst[e] : 0;
        if (ok[j]) {
            unsigned db = __float_as_uint(dinv[s]);
            db += 0x7FFF + ((db >> 16) & 1);            // rne bf16
            sv[j] = (unsigned)s | (db & 0xFFFF0000u);   // src in low16, dinv_src bf16 in high16
            atomicAdd(&hist[dv[j] >> 8], 1);
        }
    }
    __syncthreads();
    int v = hist[tid];
    ofs[tid] = v;
    __syncthreads();
    for (int off = 1; off < 256; off <<= 1) {
        int a = (tid >= off) ? ofs[tid - off] : 0;
        __syncthreads();
        ofs[tid] += a;
        __syncthreads();
    }
    if (tid == 255) totS = ofs[255];
    int excl = ofs[tid] - v;
    __syncthreads();
    ofs[tid] = excl;
    if (tid < NBUK && v > 0) bbaseL[tid] = atomicAdd(&gbkcur[tid], v);
    __syncthreads();
    #pragma unroll
    for (int j = 0; j < 8; ++j) {
        if (ok[j]) {
            int b = dv[j] >> 8;
            int idx = atomicAdd(&lcnt[b], 1);
            stage[ofs[b] + idx] = make_uint2(sv[j], (unsigned)dv[j]);
        }
    }
    __syncthreads();
    int tot = totS;
    #pragma unroll
    for (int j = 0; j < 8; ++j) {
        int slot = j * 256 + tid;
        if (slot < tot) {
            uint2 p = stage[slot];
            int b = (int)(p.y >> 8);
            ebuf[bbaseL[b] + (slot - ofs[b])] = p;
        }
    }
}

// ---------------- phase B: place edges into padded CSR; LDS cursors; pad fill;
// also finalizes rowptr (+ scan-block offset) into rp2 ----------------
__global__ __launch_bounds__(256) void k_place(const uint2* __restrict__ ebuf,
                                               const int* __restrict__ bbase,
                                               const int* __restrict__ rowptr,
                                               const int* __restrict__ blkOff,
                                               int* __restrict__ rp2,
                                               unsigned* __restrict__ ew) {
    __shared__ int lcur[256];
    int b = blockIdx.x, t = threadIdx.x;
    int lo = b * 256;
    int n = NNODES - lo; if (n > 256) n = 256;
    if (t < n) {
        int node = lo + t;
        int base = rowptr[node] + blkOff[node >> 10];
        lcur[t] = base;
        rp2[node] = base;
    }
    __syncthreads();
    int e0 = bbase[b], e1 = bbase[b + 1];
    for (int e = e0 + t; e < e1; e += 256) {
        uint2 p = ebuf[e];
        int pos = atomicAdd(&lcur[p.y & 255], 1);
        ew[pos] = p.x;
    }
    __syncthreads();
    if (t < n) {
        int idx = lo + t + 1;
        int end = (idx < NNODES) ? (rowptr[idx] + blkOff[idx >> 10]) : rp2[NNODES];
        for (int q = lcur[t]; q < end; ++q) ew[q] = NNODES;   // sentinel: weight bits = 0
    }
}

// ---------------- FUSED [BN+ReLU] + gather + MFMA GEMM ----------------
// a_i = dinv_i*( sum_e w_e*f(row_src) + dinv_i*f(row_i) ), w_e = bf16(dinv_src) from ew.
// f = relu(BN(.)) for CH layers (per-lane channel constants, computed once/wave) or
// identity for layer 0. Gather writes the swizzled LDS A-tile; MFMA consumes W in
// KS 14 KB hi/lo chunks through one staging buffer; next chunk register-prefetched.
// POOL: two-level pooled reduction — per-tile LDS pbuf[graph-g0][ch] (LDS atomics),
// then ~gspan*CH global atomics per block (30x fewer than per-element; R9 lesson).
template<int CPACK, int RB, int KS, bool BN, bool POOL>
__global__ __launch_bounds__(512, 8) void k_fused(
    const unsigned* __restrict__ h, const unsigned* __restrict__ Whi,
    const unsigned* __restrict__ Wlo, const float* __restrict__ bias,
    const int* __restrict__ rowptr, const unsigned* __restrict__ ew,
    const float* __restrict__ dinv,
    const float* __restrict__ pgsum, const float* __restrict__ pgsq,
    const float* __restrict__ gamma, const float* __restrict__ beta,
    const int* __restrict__ batch, float* __restrict__ gpool,
    unsigned* __restrict__ Zout, float* __restrict__ gsum, float* __restrict__ gsq) {
    constexpr int RBY = KS * 64;                  // A-tile row bytes
    __shared__ __align__(16) unsigned char aS[64 * RBY];
    __shared__ __align__(16) unsigned char wB[112 * 128];   // 14 KB W chunk
    __shared__ float sSum[CH], sSq[CH];
    __shared__ float pbuf[GSPAN * CH];            // POOL: per-tile per-graph sums (3.2 KB)
    int tid = threadIdx.x;
    for (int i = tid; i < CH; i += 512) { sSum[i] = 0.f; sSq[i] = 0.f; }
    if (POOL) for (int i = tid; i < GSPAN * CH; i += 512) pbuf[i] = 0.f;
    // stage W chunk 0 (hi, k-pair 0)
    for (int idx = tid; idx < 112 * 8; idx += 512) {
        int c = idx >> 3, j = idx & 7;
        uint4 v = *(const uint4*)(Whi + c * (KS * 16) + j * 4);
        *(uint4*)(wB + ((unsigned)(c * 128 + j * 16) ^ ((c & 7) << 4))) = v;
    }
    int w = tid >> 6, lane = tid & 63;
    int row0 = blockIdx.x * 64;
    const char* __restrict__ hb = (const char*)h;
    bool act = lane < CPACK;
    unsigned l4 = (unsigned)(lane << 2);
    // per-lane (= per channel-pair) BN constants, once per wave
    float scx = 0.f, shx = 0.f, scy = 0.f, shy = 0.f;
    if (BN && act) {
        float sx = 0.f, sy = 0.f, qx = 0.f, qy = 0.f;
        #pragma unroll
        for (int sh = 0; sh < NSHARD; ++sh) {
            float2 s2 = ((const float2*)(pgsum + sh * SHSTRIDE))[lane];
            float2 q2 = ((const float2*)(pgsq + sh * SHSTRIDE))[lane];
            sx += s2.x; sy += s2.y; qx += q2.x; qy += q2.y;
        }
        constexpr float invN = 1.f / NNODES;
        float2 g2 = ((const float2*)gamma)[lane];
        float2 b2 = ((const float2*)beta)[lane];
        float mx = sx * invN, my = sy * invN;
        float vx = qx * invN - mx * mx, vy = qy * invN - my * my;
        scx = g2.x * rsqrtf(vx + BN_EPS); shx = b2.x - mx * scx;
        scy = g2.y * rsqrtf(vy + BN_EPS); shy = b2.y - my * scy;
    }
    // ---- gather phase: wave w builds rows w*8 .. w*8+7 (R6-proven single-row loop) ----
    for (int ni = 0; ni < 8; ++ni) {
        int r = w * 8 + ni;
        int node = row0 + r;
        float ax = 0.f, ay = 0.f, di = 0.f;
        if (node < NNODES) {
            int p0 = __builtin_amdgcn_readfirstlane(rowptr[node]);
            int p1 = __builtin_amdgcn_readfirstlane(rowptr[node + 1]);
            di = dinv[node];
            if (act) {
                unsigned hv = h[(size_t)node * CPACK + lane];   // self term
                float fx = unp_lo(hv), fy = unp_hi(hv);
                if (BN) {
                    fx = fmaxf(fmaf(fx, scx, shx), 0.f);
                    fy = fmaxf(fmaf(fy, scy, shy), 0.f);
                }
                ax = di * fx; ay = di * fy;
            }
            const uint4* __restrict__ E4 = (const uint4*)(ew + p0);
            int n8 = (p1 - p0) >> 3;
            for (int q = 0; q < n8; ++q) {
                uint4 ea = E4[2 * q];
                uint4 eb = E4[2 * q + 1];
                unsigned ee[8] = {ea.x, ea.y, ea.z, ea.w, eb.x, eb.y, eb.z, eb.w};
                if (act) {
                    unsigned v[8];
                    #pragma unroll
                    for (int t = 0; t < 8; ++t)
                        v[t] = *(const unsigned*)(hb + (ee[t] & 0xFFFFu) * (unsigned)RB + l4);
                    #pragma unroll
                    for (int t = 0; t < 8; ++t) {
                        float vx = unp_lo(v[t]), vy = unp_hi(v[t]);
                        if (BN) {
                            vx = fmaxf(fmaf(vx, scx, shx), 0.f);
                            vy = fmaxf(fmaf(vy, scy, shy), 0.f);
                        }
                        float wgt = unp_hi(ee[t]);   // bf16(dinv_src); 0 on pad sentinels
                        ax = fmaf(wgt, vx, ax); ay = fmaf(wgt, vy, ay);
                    }
                }
            }
        }
        unsigned val = act ? pack_bf16(di * ax, di * ay) : 0u;
        if (lane < RBY / 4)
            *(unsigned*)(aS + ((unsigned)(r * RBY + lane * 4) ^ ((r & 7) << 4))) = val;
    }
    __syncthreads();
    // ---- MFMA phase: KS chunks; next chunk register-prefetched during MFMAs ----
    int wm = w & 3, wh = w >> 2;          // m-tile, n-half (wh=0: nt 0..3, wh=1: nt 4..6)
    int lr = lane & 15, lg = lane >> 4;
    f32x4 acc[4];
    #pragma unroll
    for (int nt = 0; nt < 4; ++nt) acc[nt] = (f32x4){0.f, 0.f, 0.f, 0.f};
    int ar = wm * 16 + lr;
    unsigned aswz = (unsigned)((ar & 7) << 4);
    uint4 pv0, pv1;
    #pragma unroll
    for (int ch = 0; ch < KS; ++ch) {
        if (ch + 1 < KS) {   // prefetch next chunk into registers (overlaps MFMAs)
            const unsigned* Wp = (ch + 1 >= KS / 2) ? Wlo : Whi;
            int pn = (KS > 2) ? ((ch + 1) & 1) : 0;
            {
                int c = tid >> 3, j = tid & 7;
                pv0 = *(const uint4*)(Wp + c * (KS * 16) + pn * 32 + j * 4);
            }
            if (tid < 384) {
                int idx = tid + 512;
                int c = idx >> 3, j = idx & 7;
                pv1 = *(const uint4*)(Wp + c * (KS * 16) + pn * 32 + j * 4);
            }
        }
        int p = (KS > 2) ? (ch & 1) : 0;
        #pragma unroll
        for (int ksl = 0; ksl < 2; ++ksl) {
            int ks = p * 2 + ksl;
            short8 af = *(const short8*)(aS + ((unsigned)(ar * RBY + ks * 64 + lg * 16) ^ aswz));
            #pragma unroll
            for (int nt = 0; nt < 4; ++nt) {
                if (wh && nt == 3) continue;   // only 7 n-tiles total
                int c = (wh * 4 + nt) * 16 + lr;
                short8 bb = *(const short8*)(wB + ((unsigned)(c * 128 + ksl * 64 + lg * 16) ^ ((c & 7) << 4)));
                acc[nt] = __builtin_amdgcn_mfma_f32_16x16x32_bf16(af, bb, acc[nt], 0, 0, 0);
            }
        }
        if (ch + 1 < KS) {
            __syncthreads();   // all reads of current chunk done
            {
                int c = tid >> 3, j = tid & 7;
                *(uint4*)(wB + ((unsigned)(c * 128 + j * 16) ^ ((c & 7) << 4))) = pv0;
            }
            if (tid < 384) {
                int idx = tid + 512;
                int c = idx >> 3, j = idx & 7;
                *(uint4*)(wB + ((unsigned)(c * 128 + j * 16) ^ ((c & 7) << 4))) = pv1;
            }
            __syncthreads();
        }
    }
    // epilogue: bias; then packed bf16 store (layers 0-2) or LDS-reduced pooling
    // (layer 3); BN stats always.
    int g0 = 0, gspan = 0;
    int g4[4];
    if (POOL) {
        int lastRow = row0 + 63; if (lastRow >= NNODES) lastRow = NNODES - 1;
        g0 = __builtin_amdgcn_readfirstlane(batch[row0]);
        gspan = __builtin_amdgcn_readfirstlane(batch[lastRow]) - g0 + 1;
        if (gspan > GSPAN) gspan = GSPAN;
        #pragma unroll
        for (int r = 0; r < 4; ++r) {
            int row = row0 + wm * 16 + lg * 4 + r;
            g4[r] = (row < NNODES) ? batch[row] : g0;
        }
    }
    #pragma unroll
    for (int nt = 0; nt < 4; ++nt) {
        if (wh && nt == 3) continue;
        int c = (wh * 4 + nt) * 16 + lr;
        bool cok = c < CH;
        float bcol = cok ? bias[c] : 0.f;
        float s = 0.f, q = 0.f;
        #pragma unroll
        for (int r = 0; r < 4; ++r) {
            int row = row0 + wm * 16 + lg * 4 + r;
            float z = acc[nt][r] + bcol;
            float zo = __shfl_xor(z, 1);
            if (cok && row < NNODES) {
                if (POOL) {
                    int goff = g4[r] - g0;
                    if (goff < GSPAN) atomicAdd(&pbuf[goff * CH + c], z);
                    else atomicAdd(&gpool[g4[r] * CH + c], z);   // pathological span
                } else {
                    if ((lane & 1) == 0)
                        Zout[(size_t)row * 50 + (c >> 1)] = pack_bf16(z, zo);
                }
                s += z; q += z * z;
            }
        }
        s += __shfl_xor(s, 16); s += __shfl_xor(s, 32);
        q += __shfl_xor(q, 16); q += __shfl_xor(q, 32);
        if (lane < 16 && cok) { atomicAdd(&sSum[c], s); atomicAdd(&sSq[c], q); }
    }
    __syncthreads();
    if (POOL) {   // flush per-graph tile sums: ~gspan*CH global atomics per block
        for (int idx = tid; idx < gspan * CH; idx += 512) {
            float v = pbuf[idx];
            if (v != 0.f) atomicAdd(&gpool[(g0 + idx / CH) * CH + (idx % CH)], v);
        }
    }
    int sh = (blockIdx.x & (NSHARD - 1)) * SHSTRIDE;
    if (tid < CH) { atomicAdd(&gsum[sh + tid], sSum[tid]); atomicAdd(&gsq[sh + tid], sSq[tid]); }
}

// ---------------- out = leakyrelu( (BN-affine of raw pooled sums) @ Wout + bout, 0.1 ) ----------------
// gS[c] = scx_c * S[gid][c] + n_gid * shx_c  (linearity of BN over the pooled sum)
__global__ __launch_bounds__(256) void k_out(const float* __restrict__ g,
                                             const int* __restrict__ batch,
                                             const float* __restrict__ gsum,
                                             const float* __restrict__ gsq,
                                             const float* __restrict__ gamma,
                                             const float* __restrict__ beta,
                                             const float* __restrict__ Wout,
                                             const float* __restrict__ bout,
                                             float* __restrict__ out) {
    __shared__ float gS[CH];
    __shared__ int se[2];
    int gid = blockIdx.x, tid = threadIdx.x;
    if (tid == 0) {
        int lo = 0, hi = NNODES;
        while (lo < hi) { int m = (lo + hi) >> 1; if (batch[m] < gid) lo = m + 1; else hi = m; }
        se[0] = lo;
        hi = NNODES;
        while (lo < hi) { int m = (lo + hi) >> 1; if (batch[m] < gid + 1) lo = m + 1; else hi = m; }
        se[1] = lo;
    }
    __syncthreads();
    float n = (float)(se[1] - se[0]);
    if (tid < 50) {
        float su = 0.f, sv = 0.f, qu = 0.f, qv = 0.f;
        #pragma unroll
        for (int sh = 0; sh < NSHARD; ++sh) {
            float2 s2 = ((const float2*)(gsum + sh * SHSTRIDE))[tid];
            float2 q2 = ((const float2*)(gsq + sh * SHSTRIDE))[tid];
            su += s2.x; sv += s2.y; qu += q2.x; qv += q2.y;
        }
        constexpr float invN = 1.f / NNODES;
        float2 g2 = ((const float2*)gamma)[tid];
        float2 b2 = ((const float2*)beta)[tid];
        float mx = su * invN, my = sv * invN;
        float vx = qu * invN - mx * mx, vy = qv * invN - my * my;
        float scx = g2.x * rsqrtf(vx + BN_EPS), shx = b2.x - mx * scx;
        float scy = g2.y * rsqrtf(vy + BN_EPS), shy = b2.y - my * scy;
        float2 S = ((const float2*)(g + gid * CH))[tid];
        gS[2 * tid] = S.x * scx + n * shx;
        gS[2 * tid + 1] = S.y * scy + n * shy;
    }
    __syncthreads();
    if (tid >= 200) return;
    float acc = bout[tid];
    for (int k = 0; k < CH; ++k) acc += gS[k] * Wout[k * 200 + tid];
    out[gid * 200 + tid] = acc > 0.f ? acc : 0.1f * acc;
}

extern "C" void kernel_launch(void* const* d_in, const int* in_sizes, int n_in,
                              void* d_out, int out_size, void* d_ws, size_t ws_size,
                              hipStream_t stream) {
    const float* x = (const float*)d_in[0];
    const int* ei = (const int*)d_in[1];
    const int* batch = (const int*)d_in[2];
    const float* W0 = (const float*)d_in[3];
    const float* Wrest = (const float*)d_in[4];
    const float* b = (const float*)d_in[5];
    const float* gamma = (const float*)d_in[6];
    const float* beta = (const float*)d_in[7];
    const float* Wout = (const float*)d_in[8];
    const float* bout = (const float*)d_in[9];
    float* out = (float*)d_out;
    const int* srcA = ei;
    const int* dstA = ei + NEDGES;

    char* wsb = (char*)d_ws;
    size_t off = 0;
    auto alloc = [&](size_t elems) -> void* {
        void* p = (void*)(wsb + off);
        off += ((elems + 7) & ~(size_t)7) * 4;
        return p;
    };
    int* cnt = (int*)alloc(NNODES);
    int* rowptr = (int*)alloc(NNODES + 1);   // pre-offset (per-scan-block local)
    int* rp2 = (int*)alloc(NNODES + 1);      // finalized rowptr
    float* dinv = (float*)alloc(NNODES);
    int* scanBlk = (int*)alloc(64);
    int* scanOff = (int*)alloc(64);
    int* bcnt = (int*)alloc(256);
    int* bbase = (int*)alloc(256);
    int* gbkcur = (int*)alloc(256);
    float* stats = (float*)alloc(NSHARD * SHSTRIDE);
    unsigned* ew = (unsigned*)alloc((size_t)NEDGES + 8 * NNODES);  // padded CSR (src|dinv_bf16)
    uint2* ebuf = (uint2*)alloc(2 * (size_t)NEDGES);               // bucket-major staging
    unsigned* xb = (unsigned*)alloc((size_t)(NNODES + 1) * 17);
    unsigned* wthi = (unsigned*)alloc(3 * 112 * 64);
    unsigned* wtlo = (unsigned*)alloc(3 * 112 * 64);
    unsigned* w0hi = (unsigned*)alloc(112 * 32);
    unsigned* w0lo = (unsigned*)alloc(112 * 32);
    unsigned* Z0 = (unsigned*)alloc((size_t)(NNODES + 1) * 50);    // ping-pong activations
    unsigned* Z1 = (unsigned*)alloc((size_t)(NNODES + 1) * 50);
    float* gbuf = (float*)alloc((size_t)NGRAPH * CH);              // raw per-graph channel sums
    (void)ws_size; (void)n_in; (void)in_sizes; (void)out_size;

    hipLaunchKernelGGL(k_prep, dim3(((NNODES + 1) * 17 + 255) / 256), dim3(256), 0, stream,
                       x, xb, cnt, stats, gbuf, Wrest, wthi, wtlo, W0, w0hi, w0lo, Z0, Z1);
    hipLaunchKernelGGL(k_hist, dim3((NEDGES + 255) / 256), dim3(256), 0, stream, dstA, cnt);
    hipLaunchKernelGGL(k_scan1, dim3(SCAN_BLOCKS), dim3(SCAN_TPB), 0, stream,
                       cnt, rowptr, scanBlk, dinv, bcnt);
    hipLaunchKernelGGL(k_scan2b, dim3(1), dim3(256), 0, stream,
                       scanBlk, scanOff, rp2, bcnt, bbase, gbkcur);
    hipLaunchKernelGGL(k_bin, dim3((NEDGES + BEPW - 1) / BEPW), dim3(256), 0, stream,
                       srcA, dstA, dinv, gbkcur, ebuf);
    hipLaunchKernelGGL(k_place, dim3(NBUK), dim3(256), 0, stream,
                       ebuf, bbase, rowptr, scanOff, rp2, ew);

    const int NTILE = (NNODES + 63) / 64;
    // ---- layer 0: fused gather(xb, identity) + MFMA (K=64) -> Z0 ----
    hipLaunchKernelGGL((k_fused<17, 68, 2, false, false>), dim3(NTILE), dim3(512), 0, stream,
                       xb, w0hi, w0lo, b, rp2, ew, dinv,
                       (const float*)nullptr, (const float*)nullptr,
                       (const float*)nullptr, (const float*)nullptr,
                       (const int*)nullptr, (float*)nullptr,
                       Z0, stats + 0 * 128, stats + 512 + 0 * 128);
    // ---- layers 1..2: fused BN+relu+gather(Zprev) + MFMA (K=128), ping-pong ----
    unsigned* Zp[3] = {Z0, Z1, Z0};
    for (int l = 1; l < 3; ++l) {
        hipLaunchKernelGGL((k_fused<50, 200, 4, true, false>), dim3(NTILE), dim3(512), 0, stream,
                           Zp[l - 1], wthi + (l - 1) * 7168, wtlo + (l - 1) * 7168, b + l * CH,
                           rp2, ew, dinv,
                           stats + (l - 1) * 128, stats + 512 + (l - 1) * 128,
                           gamma + (l - 1) * CH, beta + (l - 1) * CH,
                           (const int*)nullptr, (float*)nullptr,
                           Zp[l], stats + l * 128, stats + 512 + l * 128);
    }
    // ---- layer 3: fused BN+relu+gather + MFMA + LDS-reduced pooling (no Z store) ----
    hipLaunchKernelGGL((k_fused<50, 200, 4, true, true>), dim3(NTILE), dim3(512), 0, stream,
                       Zp[2], wthi + 2 * 7168, wtlo + 2 * 7168, b + 3 * CH,
                       rp2, ew, dinv,
                       stats + 2 * 128, stats + 512 + 2 * 128,
                       gamma + 2 * CH, beta + 2 * CH,
                       batch, gbuf,
                       (unsigned*)nullptr, stats + 3 * 128, stats + 512 + 3 * 128);
    hipLaunchKernelGGL(k_out, dim3(NGRAPH), dim3(256), 0, stream,
                       gbuf, batch, stats + 3 * 128, stats + 512 + 3 * 128,
                       gamma + 3 * CH, beta + 3 * CH, Wout, bout, out);
}

// Round 11
// 322.079 us; speedup vs baseline: 1.1691x; 1.0602x over previous
//
#include <hip/hip_runtime.h>

#define NNODES 50000
#define NEDGES 800000
#define NGRAPH 500
#define CH 100
#define CIN0 33
#define BN_EPS 1e-5f
#define NSHARD 8
#define SHSTRIDE 1024   // floats per shard: [4 layers][sum128|sq128]
#define NBUK 196        // = ceil(NNODES/256); bucket b covers dst nodes [b*256, b*256+256)
#define BEPW 2048       // edges per workgroup in k_bin

#define SCAN_TPB 256
#define SCAN_IPT 4
#define SCAN_TILE (SCAN_TPB * SCAN_IPT)
#define SCAN_BLOCKS ((NNODES + SCAN_TILE - 1) / SCAN_TILE)

typedef __attribute__((ext_vector_type(8))) short short8;
typedef __attribute__((ext_vector_type(4))) float f32x4;

// pack two fp32 into (bf16(x) | bf16(y)<<16), round-to-nearest-even
__device__ inline unsigned pack_bf16(float x, float y) {
    unsigned xb = __float_as_uint(x);
    unsigned yb = __float_as_uint(y);
    xb += 0x7FFF + ((xb >> 16) & 1);
    yb += 0x7FFF + ((yb >> 16) & 1);
    return (xb >> 16) | (yb & 0xFFFF0000u);
}
__device__ inline float unp_lo(unsigned v) { return __uint_as_float(v << 16); }
__device__ inline float unp_hi(unsigned v) { return __uint_as_float(v & 0xFFFF0000u); }

// ---------------- fused prep: zero counters/stats, pack x (unscaled bf16),
// pack W hi/lo, pack W0 hi/lo, zero Z sentinels ----------------
__global__ void k_prep(const float* __restrict__ x, unsigned* __restrict__ xb,
                       int* __restrict__ cnt, float* __restrict__ stats,
                       const float* __restrict__ Wrest, unsigned* __restrict__ whi,
                       unsigned* __restrict__ wlo,
                       const float* __restrict__ W0, unsigned* __restrict__ w0hi,
                       unsigned* __restrict__ w0lo,
                       unsigned* __restrict__ Z0, unsigned* __restrict__ Z1) {
    int i = blockIdx.x * blockDim.x + threadIdx.x;
    if (i < (NNODES + 1) * 17) {           // pack x -> bf16 (UNSCALED; dinv rides on edges)
        int r = i / 17, s = i - r * 17;
        if (r >= NNODES) xb[i] = 0u;       // zero sentinel row
        else {
            float a = x[r * CIN0 + 2 * s];
            float b = (2 * s + 1 < CIN0) ? x[r * CIN0 + 2 * s + 1] : 0.f;
            xb[i] = pack_bf16(a, b);
        }
    }
    if (i < NNODES) cnt[i] = 0;
    if (i < NSHARD * SHSTRIDE) stats[i] = 0.f;
    if (i < 3 * 112 * 64) {                // Wrest^T hi/lo, K padded to 128
        int l = i / 7168, rem = i % 7168;
        int c = rem >> 6, ku = rem & 63;
        int k0 = 2 * ku;
        float w0 = 0.f, w1 = 0.f;
        if (c < CH && k0 < CH) {
            w0 = Wrest[l * 10000 + k0 * CH + c];
            if (k0 + 1 < CH) w1 = Wrest[l * 10000 + (k0 + 1) * CH + c];
        }
        unsigned hh = pack_bf16(w0, w1);
        whi[i] = hh;
        wlo[i] = pack_bf16(w0 - unp_lo(hh), w1 - unp_hi(hh));
    }
    if (i < 112 * 32) {                    // W0^T hi/lo, K padded to 64
        int c = i >> 5, ku = i & 31;
        int k0 = 2 * ku;
        float w0 = 0.f, w1 = 0.f;
        if (c < CH && k0 < CIN0) {
            w0 = W0[k0 * CH + c];
            if (k0 + 1 < CIN0) w1 = W0[(k0 + 1) * CH + c];
        }
        unsigned hh = pack_bf16(w0, w1);
        w0hi[i] = hh;
        w0lo[i] = pack_bf16(w0 - unp_lo(hh), w1 - unp_hi(hh));
    }
    if (i < 50) {                          // zero Z sentinel rows (read via pad edges)
        Z0[(size_t)NNODES * 50 + i] = 0u;
        Z1[(size_t)NNODES * 50 + i] = 0u;
    }
}

// ---------------- in-degree histogram over dst ----------------
__global__ void k_hist(const int* __restrict__ dst, int* __restrict__ cnt) {
    int e = blockIdx.x * blockDim.x + threadIdx.x;
    if (e < NEDGES) atomicAdd(&cnt[dst[e]], 1);
}

// ---------------- exclusive scan of padded counts -> rowptr; dinv; per-bucket edge counts ----------------
__global__ void k_scan1(const int* __restrict__ cnt, int* __restrict__ rowptr,
                        int* __restrict__ blkSums, float* __restrict__ dinv,
                        int* __restrict__ bcnt) {
    __shared__ int ts[SCAN_TPB];
    __shared__ int bsum[4];
    int tid = threadIdx.x;
    if (tid < 4) bsum[tid] = 0;
    int base = blockIdx.x * SCAN_TILE + tid * SCAN_IPT;
    int v[SCAN_IPT];
    int s = 0, cact = 0;
    #pragma unroll
    for (int j = 0; j < SCAN_IPT; ++j) {
        int i = base + j;
        int c = (i < NNODES) ? cnt[i] : 0;
        if (i < NNODES) dinv[i] = rsqrtf((float)(c + 1));
        v[j] = (c + 7) & ~7;   // pad each row to multiple of 8 edges
        s += v[j];
        cact += c;
    }
    ts[tid] = s;
    __syncthreads();
    atomicAdd(&bsum[(tid * SCAN_IPT) >> 8], cact);
    for (int off = 1; off < SCAN_TPB; off <<= 1) {
        int add = (tid >= off) ? ts[tid - off] : 0;
        __syncthreads();
        ts[tid] += add;
        __syncthreads();
    }
    int run = ts[tid] - s;
    #pragma unroll
    for (int j = 0; j < SCAN_IPT; ++j) {
        int i = base + j;
        if (i < NNODES) rowptr[i] = run;
        run += v[j];
    }
    if (tid == SCAN_TPB - 1) blkSums[blockIdx.x] = ts[tid];
    if (tid < 4) {
        int b = blockIdx.x * 4 + tid;
        if (b < NBUK) bcnt[b] = bsum[tid];
    }
}

// ---------------- scan2 (block offsets, serial) + bucket scan, one 256-thr block ----------------
__global__ void k_scan2b(const int* __restrict__ blkSums, int* __restrict__ blkOff,
                         int* __restrict__ rp2, const int* __restrict__ bcnt,
                         int* __restrict__ bbase, int* __restrict__ gbkcur) {
    __shared__ int ts[256];
    int t = threadIdx.x;
    if (t == 0) {
        int run = 0;
        for (int i = 0; i < SCAN_BLOCKS; ++i) { blkOff[i] = run; run += blkSums[i]; }
        rp2[NNODES] = run;   // total padded edges (finalized rowptr end)
    }
    int v = (t < NBUK) ? bcnt[t] : 0;
    ts[t] = v;
    __syncthreads();
    for (int off = 1; off < 256; off <<= 1) {
        int a = (t >= off) ? ts[t - off] : 0;
        __syncthreads();
        ts[t] += a;
        __syncthreads();
    }
    int excl = ts[t] - v;
    if (t < NBUK) { bbase[t] = excl; gbkcur[t] = excl; }
    if (t == NBUK - 1) bbase[NBUK] = ts[t];
}

// ---------------- phase A: bin edges by dst-bucket; pack (src | bf16(dinv[src])<<16) ----------------
__global__ __launch_bounds__(256) void k_bin(const int* __restrict__ src,
                                             const int* __restrict__ dst,
                                             const float* __restrict__ dinv,
                                             int* __restrict__ gbkcur,
                                             uint2* __restrict__ ebuf) {
    __shared__ int hist[256], ofs[256], lcnt[256], bbaseL[256];
    __shared__ int totS;
    __shared__ uint2 stage[BEPW];   // 16 KB
    int tid = threadIdx.x;
    hist[tid] = 0; lcnt[tid] = 0;
    __syncthreads();
    int e0 = blockIdx.x * BEPW;
    unsigned sv[8]; int dv[8]; bool ok[8];
    #pragma unroll
    for (int j = 0; j < 8; ++j) {
        int e = e0 + j * 256 + tid;
        ok[j] = e < NEDGES;
        int s = ok[j] ? src[e] : 0;
        dv[j] = ok[j] ? dst[e] : 0;
        if (ok[j]) {
            unsigned db = __float_as_uint(dinv[s]);
            db += 0x7FFF + ((db >> 16) & 1);            // rne bf16
            sv[j] = (unsigned)s | (db & 0xFFFF0000u);   // src in low16, dinv_src bf16 in high16
            atomicAdd(&hist[dv[j] >> 8], 1);
        }
    }
    __syncthreads();
    int v = hist[tid];
    ofs[tid] = v;
    __syncthreads();
    for (int off = 1; off < 256; off <<= 1) {
        int a = (tid >= off) ? ofs[tid - off] : 0;
        __syncthreads();
        ofs[tid] += a;
        __syncthreads();
    }
    if (tid == 255) totS = ofs[255];
    int excl = ofs[tid] - v;
    __syncthreads();
    ofs[tid] = excl;
    if (tid < NBUK && v > 0) bbaseL[tid] = atomicAdd(&gbkcur[tid], v);
    __syncthreads();
    #pragma unroll
    for (int j = 0; j < 8; ++j) {
        if (ok[j]) {
            int b = dv[j] >> 8;
            int idx = atomicAdd(&lcnt[b], 1);
            stage[ofs[b] + idx] = make_uint2(sv[j], (unsigned)dv[j]);
        }
    }
    __syncthreads();
    int tot = totS;
    #pragma unroll
    for (int j = 0; j < 8; ++j) {
        int slot = j * 256 + tid;
        if (slot < tot) {
            uint2 p = stage[slot];
            int b = (int)(p.y >> 8);
            ebuf[bbaseL[b] + (slot - ofs[b])] = p;
        }
    }
}

// ---------------- phase B: place edges into padded CSR; LDS cursors; pad fill;
// also finalizes rowptr (+ scan-block offset) into rp2 ----------------
__global__ __launch_bounds__(256) void k_place(const uint2* __restrict__ ebuf,
                                               const int* __restrict__ bbase,
                                               const int* __restrict__ rowptr,
                                               const int* __restrict__ blkOff,
                                               int* __restrict__ rp2,
                                               unsigned* __restrict__ ew) {
    __shared__ int lcur[256];
    int b = blockIdx.x, t = threadIdx.x;
    int lo = b * 256;
    int n = NNODES - lo; if (n > 256) n = 256;
    if (t < n) {
        int node = lo + t;
        int base = rowptr[node] + blkOff[node >> 10];
        lcur[t] = base;
        rp2[node] = base;
    }
    __syncthreads();
    int e0 = bbase[b], e1 = bbase[b + 1];
    for (int e = e0 + t; e < e1; e += 256) {
        uint2 p = ebuf[e];
        int pos = atomicAdd(&lcur[p.y & 255], 1);
        ew[pos] = p.x;
    }
    __syncthreads();
    if (t < n) {
        int idx = lo + t + 1;
        int end = (idx < NNODES) ? (rowptr[idx] + blkOff[idx >> 10]) : rp2[NNODES];
        for (int q = lcur[t]; q < end; ++q) ew[q] = NNODES;   // sentinel: weight bits = 0
    }
}

// ---------------- FUSED [BN+ReLU] + gather + MFMA GEMM (R8-proven form) ----------------
// a_i = dinv_i*( sum_e w_e*f(row_src) + dinv_i*f(row_i) ), w_e = bf16(dinv_src) from ew.
// f = relu(BN(.)) for CH layers (per-lane channel constants, computed once/wave) or
// identity for layer 0. Gather writes the swizzled LDS A-tile; MFMA consumes W in
// KS 14 KB hi/lo chunks through one staging buffer (~31.5 KB LDS, 4 blocks/CU).
// Next W chunk is register-prefetched during MFMAs so only ds_write sits between barriers.
template<int CPACK, int RB, int KS, bool BN>
__global__ __launch_bounds__(512, 8) void k_fused(
    const unsigned* __restrict__ h, const unsigned* __restrict__ Whi,
    const unsigned* __restrict__ Wlo, const float* __restrict__ bias,
    const int* __restrict__ rowptr, const unsigned* __restrict__ ew,
    const float* __restrict__ dinv,
    const float* __restrict__ pgsum, const float* __restrict__ pgsq,
    const float* __restrict__ gamma, const float* __restrict__ beta,
    unsigned* __restrict__ Zout, float* __restrict__ gsum, float* __restrict__ gsq) {
    constexpr int RBY = KS * 64;                  // A-tile row bytes
    __shared__ __align__(16) unsigned char aS[64 * RBY];
    __shared__ __align__(16) unsigned char wB[112 * 128];   // 14 KB W chunk
    __shared__ float sSum[CH], sSq[CH];
    int tid = threadIdx.x;
    for (int i = tid; i < CH; i += 512) { sSum[i] = 0.f; sSq[i] = 0.f; }
    // stage W chunk 0 (hi, k-pair 0)
    for (int idx = tid; idx < 112 * 8; idx += 512) {
        int c = idx >> 3, j = idx & 7;
        uint4 v = *(const uint4*)(Whi + c * (KS * 16) + j * 4);
        *(uint4*)(wB + ((unsigned)(c * 128 + j * 16) ^ ((c & 7) << 4))) = v;
    }
    int w = tid >> 6, lane = tid & 63;
    int row0 = blockIdx.x * 64;
    const char* __restrict__ hb = (const char*)h;
    bool act = lane < CPACK;
    unsigned l4 = (unsigned)(lane << 2);
    // per-lane (= per channel-pair) BN constants, once per wave
    float scx = 0.f, shx = 0.f, scy = 0.f, shy = 0.f;
    if (BN && act) {
        float sx = 0.f, sy = 0.f, qx = 0.f, qy = 0.f;
        #pragma unroll
        for (int sh = 0; sh < NSHARD; ++sh) {
            float2 s2 = ((const float2*)(pgsum + sh * SHSTRIDE))[lane];
            float2 q2 = ((const float2*)(pgsq + sh * SHSTRIDE))[lane];
            sx += s2.x; sy += s2.y; qx += q2.x; qy += q2.y;
        }
        constexpr float invN = 1.f / NNODES;
        float2 g2 = ((const float2*)gamma)[lane];
        float2 b2 = ((const float2*)beta)[lane];
        float mx = sx * invN, my = sy * invN;
        float vx = qx * invN - mx * mx, vy = qy * invN - my * my;
        scx = g2.x * rsqrtf(vx + BN_EPS); shx = b2.x - mx * scx;
        scy = g2.y * rsqrtf(vy + BN_EPS); shy = b2.y - my * scy;
    }
    // ---- gather phase: wave w builds rows w*8 .. w*8+7 (R6-proven single-row loop) ----
    for (int ni = 0; ni < 8; ++ni) {
        int r = w * 8 + ni;
        int node = row0 + r;
        float ax = 0.f, ay = 0.f, di = 0.f;
        if (node < NNODES) {
            int p0 = __builtin_amdgcn_readfirstlane(rowptr[node]);
            int p1 = __builtin_amdgcn_readfirstlane(rowptr[node + 1]);
            di = dinv[node];
            if (act) {
                unsigned hv = h[(size_t)node * CPACK + lane];   // self term
                float fx = unp_lo(hv), fy = unp_hi(hv);
                if (BN) {
                    fx = fmaxf(fmaf(fx, scx, shx), 0.f);
                    fy = fmaxf(fmaf(fy, scy, shy), 0.f);
                }
                ax = di * fx; ay = di * fy;
            }
            const uint4* __restrict__ E4 = (const uint4*)(ew + p0);
            int n8 = (p1 - p0) >> 3;
            for (int q = 0; q < n8; ++q) {
                uint4 ea = E4[2 * q];
                uint4 eb = E4[2 * q + 1];
                unsigned ee[8] = {ea.x, ea.y, ea.z, ea.w, eb.x, eb.y, eb.z, eb.w};
                if (act) {
                    unsigned v[8];
                    #pragma unroll
                    for (int t = 0; t < 8; ++t)
                        v[t] = *(const unsigned*)(hb + (ee[t] & 0xFFFFu) * (unsigned)RB + l4);
                    #pragma unroll
                    for (int t = 0; t < 8; ++t) {
                        float vx = unp_lo(v[t]), vy = unp_hi(v[t]);
                        if (BN) {
                            vx = fmaxf(fmaf(vx, scx, shx), 0.f);
                            vy = fmaxf(fmaf(vy, scy, shy), 0.f);
                        }
                        float wgt = unp_hi(ee[t]);   // bf16(dinv_src); 0 on pad sentinels
                        ax = fmaf(wgt, vx, ax); ay = fmaf(wgt, vy, ay);
                    }
                }
            }
        }
        unsigned val = act ? pack_bf16(di * ax, di * ay) : 0u;
        if (lane < RBY / 4)
            *(unsigned*)(aS + ((unsigned)(r * RBY + lane * 4) ^ ((r & 7) << 4))) = val;
    }
    __syncthreads();
    // ---- MFMA phase: KS chunks; next chunk register-prefetched during MFMAs ----
    int wm = w & 3, wh = w >> 2;          // m-tile, n-half (wh=0: nt 0..3, wh=1: nt 4..6)
    int lr = lane & 15, lg = lane >> 4;
    f32x4 acc[4];
    #pragma unroll
    for (int nt = 0; nt < 4; ++nt) acc[nt] = (f32x4){0.f, 0.f, 0.f, 0.f};
    int ar = wm * 16 + lr;
    unsigned aswz = (unsigned)((ar & 7) << 4);
    uint4 pv0, pv1;
    #pragma unroll
    for (int ch = 0; ch < KS; ++ch) {
        if (ch + 1 < KS) {   // prefetch next chunk into registers (overlaps MFMAs)
            const unsigned* Wp = (ch + 1 >= KS / 2) ? Wlo : Whi;
            int pn = (KS > 2) ? ((ch + 1) & 1) : 0;
            {
                int c = tid >> 3, j = tid & 7;
                pv0 = *(const uint4*)(Wp + c * (KS * 16) + pn * 32 + j * 4);
            }
            if (tid < 384) {
                int idx = tid + 512;
                int c = idx >> 3, j = idx & 7;
                pv1 = *(const uint4*)(Wp + c * (KS * 16) + pn * 32 + j * 4);
            }
        }
        int p = (KS > 2) ? (ch & 1) : 0;
        #pragma unroll
        for (int ksl = 0; ksl < 2; ++ksl) {
            int ks = p * 2 + ksl;
            short8 af = *(const short8*)(aS + ((unsigned)(ar * RBY + ks * 64 + lg * 16) ^ aswz));
            #pragma unroll
            for (int nt = 0; nt < 4; ++nt) {
                if (wh && nt == 3) continue;   // only 7 n-tiles total
                int c = (wh * 4 + nt) * 16 + lr;
                short8 bb = *(const short8*)(wB + ((unsigned)(c * 128 + ksl * 64 + lg * 16) ^ ((c & 7) << 4)));
                acc[nt] = __builtin_amdgcn_mfma_f32_16x16x32_bf16(af, bb, acc[nt], 0, 0, 0);
            }
        }
        if (ch + 1 < KS) {
            __syncthreads();   // all reads of current chunk done
            {
                int c = tid >> 3, j = tid & 7;
                *(uint4*)(wB + ((unsigned)(c * 128 + j * 16) ^ ((c & 7) << 4))) = pv0;
            }
            if (tid < 384) {
                int idx = tid + 512;
                int c = idx >> 3, j = idx & 7;
                *(uint4*)(wB + ((unsigned)(c * 128 + j * 16) ^ ((c & 7) << 4))) = pv1;
            }
            __syncthreads();
        }
    }
    // epilogue: bias, packed bf16 store, BN stats
    #pragma unroll
    for (int nt = 0; nt < 4; ++nt) {
        if (wh && nt == 3) continue;
        int c = (wh * 4 + nt) * 16 + lr;
        bool cok = c < CH;
        float bcol = cok ? bias[c] : 0.f;
        float s = 0.f, q = 0.f;
        #pragma unroll
        for (int r = 0; r < 4; ++r) {
            int row = row0 + wm * 16 + lg * 4 + r;
            float z = acc[nt][r] + bcol;
            float zo = __shfl_xor(z, 1);
            if (cok && row < NNODES) {
                if ((lane & 1) == 0)
                    Zout[(size_t)row * 50 + (c >> 1)] = pack_bf16(z, zo);
                s += z; q += z * z;
            }
        }
        s += __shfl_xor(s, 16); s += __shfl_xor(s, 32);
        q += __shfl_xor(q, 16); q += __shfl_xor(q, 32);
        if (lane < 16 && cok) { atomicAdd(&sSum[c], s); atomicAdd(&sSq[c], q); }
    }
    __syncthreads();
    int sh = (blockIdx.x & (NSHARD - 1)) * SHSTRIDE;
    if (tid < CH) { atomicAdd(&gsum[sh + tid], sSum[tid]); atomicAdd(&gsq[sh + tid], sSq[tid]); }
}

// ---------------- merged pool + BN + out matvec: one block per graph ----------------
// Pools this graph's bf16 Z rows (4 waves, register partials -> LDS reduce),
// applies layer-3 BN affine via linearity, then out = leakyrelu(gS @ Wout + bout).
__global__ __launch_bounds__(256) void k_out(const unsigned* __restrict__ Zl,
                                             const int* __restrict__ batch,
                                             const float* __restrict__ gsum,
                                             const float* __restrict__ gsq,
                                             const float* __restrict__ gamma,
                                             const float* __restrict__ beta,
                                             const float* __restrict__ Wout,
                                             const float* __restrict__ bout,
                                             float* __restrict__ out) {
    __shared__ float psum[4][CH];
    __shared__ float gS[CH];
    __shared__ int se[2];
    int gid = blockIdx.x, tid = threadIdx.x;
    int w = tid >> 6, lane = tid & 63;
    if (tid == 0) {
        int lo = 0, hi = NNODES;
        while (lo < hi) { int m = (lo + hi) >> 1; if (batch[m] < gid) lo = m + 1; else hi = m; }
        se[0] = lo;
        hi = NNODES;
        while (lo < hi) { int m = (lo + hi) >> 1; if (batch[m] < gid + 1) lo = m + 1; else hi = m; }
        se[1] = lo;
    }
    __syncthreads();
    int start = se[0], end = se[1];
    if (lane < 50) {
        float sx = 0.f, sy = 0.f;
        for (int r = start + w; r < end; r += 4) {
            unsigned v = Zl[(size_t)r * 50 + lane];
            sx += unp_lo(v); sy += unp_hi(v);
        }
        psum[w][2 * lane] = sx;
        psum[w][2 * lane + 1] = sy;
    }
    __syncthreads();
    float n = (float)(end - start);
    if (tid < 50) {
        float su = 0.f, sv = 0.f, qu = 0.f, qv = 0.f;
        #pragma unroll
        for (int sh = 0; sh < NSHARD; ++sh) {
            float2 s2 = ((const float2*)(gsum + sh * SHSTRIDE))[tid];
            float2 q2 = ((const float2*)(gsq + sh * SHSTRIDE))[tid];
            su += s2.x; sv += s2.y; qu += q2.x; qv += q2.y;
        }
        constexpr float invN = 1.f / NNODES;
        float2 g2 = ((const float2*)gamma)[tid];
        float2 b2 = ((const float2*)beta)[tid];
        float mx = su * invN, my = sv * invN;
        float vx = qu * invN - mx * mx, vy = qv * invN - my * my;
        float scx = g2.x * rsqrtf(vx + BN_EPS), shx = b2.x - mx * scx;
        float scy = g2.y * rsqrtf(vy + BN_EPS), shy = b2.y - my * scy;
        float Sx = psum[0][2 * tid] + psum[1][2 * tid] + psum[2][2 * tid] + psum[3][2 * tid];
        float Sy = psum[0][2 * tid + 1] + psum[1][2 * tid + 1] + psum[2][2 * tid + 1] + psum[3][2 * tid + 1];
        gS[2 * tid] = Sx * scx + n * shx;
        gS[2 * tid + 1] = Sy * scy + n * shy;
    }
    __syncthreads();
    if (tid >= 200) return;
    float acc = bout[tid];
    for (int k = 0; k < CH; ++k) acc += gS[k] * Wout[k * 200 + tid];
    out[gid * 200 + tid] = acc > 0.f ? acc : 0.1f * acc;
}

extern "C" void kernel_launch(void* const* d_in, const int* in_sizes, int n_in,
                              void* d_out, int out_size, void* d_ws, size_t ws_size,
                              hipStream_t stream) {
    const float* x = (const float*)d_in[0];
    const int* ei = (const int*)d_in[1];
    const int* batch = (const int*)d_in[2];
    const float* W0 = (const float*)d_in[3];
    const float* Wrest = (const float*)d_in[4];
    const float* b = (const float*)d_in[5];
    const float* gamma = (const float*)d_in[6];
    const float* beta = (const float*)d_in[7];
    const float* Wout = (const float*)d_in[8];
    const float* bout = (const float*)d_in[9];
    float* out = (float*)d_out;
    const int* srcA = ei;
    const int* dstA = ei + NEDGES;

    char* wsb = (char*)d_ws;
    size_t off = 0;
    auto alloc = [&](size_t elems) -> void* {
        void* p = (void*)(wsb + off);
        off += ((elems + 7) & ~(size_t)7) * 4;
        return p;
    };
    int* cnt = (int*)alloc(NNODES);
    int* rowptr = (int*)alloc(NNODES + 1);   // pre-offset (per-scan-block local)
    int* rp2 = (int*)alloc(NNODES + 1);      // finalized rowptr
    float* dinv = (float*)alloc(NNODES);
    int* scanBlk = (int*)alloc(64);
    int* scanOff = (int*)alloc(64);
    int* bcnt = (int*)alloc(256);
    int* bbase = (int*)alloc(256);
    int* gbkcur = (int*)alloc(256);
    float* stats = (float*)alloc(NSHARD * SHSTRIDE);
    unsigned* ew = (unsigned*)alloc((size_t)NEDGES + 8 * NNODES);  // padded CSR (src|dinv_bf16)
    uint2* ebuf = (uint2*)alloc(2 * (size_t)NEDGES);               // bucket-major staging
    unsigned* xb = (unsigned*)alloc((size_t)(NNODES + 1) * 17);
    unsigned* wthi = (unsigned*)alloc(3 * 112 * 64);
    unsigned* wtlo = (unsigned*)alloc(3 * 112 * 64);
    unsigned* w0hi = (unsigned*)alloc(112 * 32);
    unsigned* w0lo = (unsigned*)alloc(112 * 32);
    unsigned* Z0 = (unsigned*)alloc((size_t)(NNODES + 1) * 50);    // ping-pong activations
    unsigned* Z1 = (unsigned*)alloc((size_t)(NNODES + 1) * 50);
    (void)ws_size; (void)n_in; (void)in_sizes; (void)out_size;

    hipLaunchKernelGGL(k_prep, dim3(((NNODES + 1) * 17 + 255) / 256), dim3(256), 0, stream,
                       x, xb, cnt, stats, Wrest, wthi, wtlo, W0, w0hi, w0lo, Z0, Z1);
    hipLaunchKernelGGL(k_hist, dim3((NEDGES + 255) / 256), dim3(256), 0, stream, dstA, cnt);
    hipLaunchKernelGGL(k_scan1, dim3(SCAN_BLOCKS), dim3(SCAN_TPB), 0, stream,
                       cnt, rowptr, scanBlk, dinv, bcnt);
    hipLaunchKernelGGL(k_scan2b, dim3(1), dim3(256), 0, stream,
                       scanBlk, scanOff, rp2, bcnt, bbase, gbkcur);
    hipLaunchKernelGGL(k_bin, dim3((NEDGES + BEPW - 1) / BEPW), dim3(256), 0, stream,
                       srcA, dstA, dinv, gbkcur, ebuf);
    hipLaunchKernelGGL(k_place, dim3(NBUK), dim3(256), 0, stream,
                       ebuf, bbase, rowptr, scanOff, rp2, ew);

    const int NTILE = (NNODES + 63) / 64;
    // ---- layer 0: fused gather(xb, identity) + MFMA (K=64) -> Z0 ----
    hipLaunchKernelGGL((k_fused<17, 68, 2, false>), dim3(NTILE), dim3(512), 0, stream,
                       xb, w0hi, w0lo, b, rp2, ew, dinv,
                       (const float*)nullptr, (const float*)nullptr,
                       (const float*)nullptr, (const float*)nullptr,
                       Z0, stats + 0 * 128, stats + 512 + 0 * 128);
    // ---- layers 1..3: fused BN+relu+gather(Zprev) + MFMA (K=128), ping-pong ----
    unsigned* Zp[4] = {Z0, Z1, Z0, Z1};
    for (int l = 1; l < 4; ++l) {
        hipLaunchKernelGGL((k_fused<50, 200, 4, true>), dim3(NTILE), dim3(512), 0, stream,
                           Zp[l - 1], wthi + (l - 1) * 7168, wtlo + (l - 1) * 7168, b + l * CH,
                           rp2, ew, dinv,
                           stats + (l - 1) * 128, stats + 512 + (l - 1) * 128,
                           gamma + (l - 1) * CH, beta + (l - 1) * CH,
                           Zp[l], stats + l * 128, stats + 512 + l * 128);
    }
    // ---- merged pool + BN + out ----
    hipLaunchKernelGGL(k_out, dim3(NGRAPH), dim3(256), 0, stream,
                       Z1, batch, stats + 3 * 128, stats + 512 + 3 * 128,
                       gamma + 3 * CH, beta + 3 * CH, Wout, bout, out);
}